// Round 4
// baseline (1030.020 us; speedup 1.0000x reference)
//
#include <hip/hip_runtime.h>

// CRF loss: out[b] = logZ[b] - target[b].  B=256, S=2048, D=64.
// Round 4: broadcast via v_readlane -> SGPR -> v_fma (no LDS round-trip on the
//          critical path). 8-deep global prefetch and exact pow2 renorm kept.

#define B_ 256
#define S_ 2048
#define D_ 64

// ---------------- target scores: point + transition ----------------
__global__ __launch_bounds__(256) void target_kernel(
    const float* __restrict__ y_pred, const int* __restrict__ y_true,
    const float* __restrict__ mask, const float* __restrict__ trans,
    float* __restrict__ target)
{
    int b = blockIdx.x;
    int tid = threadIdx.x;
    const int*   yt = y_true + (size_t)b * S_;
    const float* mk = mask   + (size_t)b * S_;
    const float* yp = y_pred + (size_t)b * S_ * D_;

    float acc = 0.f;
    for (int n = tid; n < S_; n += 256) {
        int   tn = yt[n];
        float mn = mk[n];
        acc += mn * mn * yp[(size_t)n * D_ + tn];
        if (n + 1 < S_) {
            int   tn1 = yt[n + 1];
            float mn1 = mk[n + 1];
            acc += mn * mn1 * trans[tn * D_ + tn1];
        }
    }
    #pragma unroll
    for (int m = 32; m >= 1; m >>= 1) acc += __shfl_xor(acc, m, 64);
    __shared__ float sred[4];
    int wid = tid >> 6;
    if ((tid & 63) == 0) sred[wid] = acc;
    __syncthreads();
    if (tid == 0) target[b] = sred[0] + sred[1] + sred[2] + sred[3];
}

// readlane: wave-uniform pull of lane `lane`'s value into an SGPR
static __device__ __forceinline__ float rdlane(float v, int lane) {
    return __uint_as_float(__builtin_amdgcn_readlane(__float_as_uint(v), lane));
}

// ---------------- forward-algorithm scan (one wave per batch) ----------------
__global__ __launch_bounds__(64) void scan_kernel(
    const float* __restrict__ y_pred, const float* __restrict__ mask,
    const float* __restrict__ trans, const float* __restrict__ target,
    float* __restrict__ out)
{
    const int b = blockIdx.x;
    const int j = threadIdx.x;              // lane = state index j
    const float* yprow = y_pred + (size_t)b * S_ * D_;
    const float* mrow  = mask   + (size_t)b * S_;

    // ET column j in registers: et[i] = exp(trans[i][j])
    float et[D_];
    #pragma unroll
    for (int i = 0; i < D_; ++i) et[i] = __expf(trans[i * D_ + j]);

    float p  = __expf(yprow[j] * mrow[0]);
    int   K  = 0;      // exact power-of-2 renorm accumulator (logZ += K*ln2)
    float Of = 0.f;    // general masked-path log offset

    // one scan step; cs uniform across wave
    auto step = [&](float eraw, float exs, float cs, bool dorescale) {
        // matvec via readlane broadcast: sum = sum_i p_i * et[i]
        float a0 = 0.f, a1 = 0.f, a2 = 0.f, a3 = 0.f,
              a4 = 0.f, a5 = 0.f, a6 = 0.f, a7 = 0.f;
        #pragma unroll
        for (int i = 0; i < D_; i += 8) {
            a0 = fmaf(rdlane(p, i + 0), et[i + 0], a0);
            a1 = fmaf(rdlane(p, i + 1), et[i + 1], a1);
            a2 = fmaf(rdlane(p, i + 2), et[i + 2], a2);
            a3 = fmaf(rdlane(p, i + 3), et[i + 3], a3);
            a4 = fmaf(rdlane(p, i + 4), et[i + 4], a4);
            a5 = fmaf(rdlane(p, i + 5), et[i + 5], a5);
            a6 = fmaf(rdlane(p, i + 6), et[i + 6], a6);
            a7 = fmaf(rdlane(p, i + 7), et[i + 7], a7);
        }
        float sum = ((a0 + a1) + (a2 + a3)) + ((a4 + a5) + (a6 + a7));

        if (cs == 1.0f) {
            p = sum * exs;                       // deferred normalization
        } else {
            // general masked path (rare; matches reference exactly for 0/1 mask)
            float sj   = __logf(p);
            float outn = __logf(sum) + eraw * cs;
            float ns   = cs * outn + (1.f - cs) * sj;
            float M = ns;
            #pragma unroll
            for (int m = 1; m <= 32; m <<= 1) M = fmaxf(M, __shfl_xor(M, m, 64));
            p = __expf(ns - M);
            Of += M;
        }
        if (dorescale) {
            // exact power-of-2 rescale keyed off lane0's exponent
            unsigned pb0 = __builtin_amdgcn_readfirstlane(__float_as_uint(p));
            int k = (int)((pb0 >> 23) & 0xffu) - 127;
            float sc = __uint_as_float((unsigned)(127 - k) << 23);
            p *= sc;                              // exact in fp32
            K += k;
        }
    };

    // prologue: issue loads for group 0 (t = 1..8)
    float e_nxt[8], c_nxt[8], e_cur[8], c_cur[8], ex[8];
    #pragma unroll
    for (int s = 0; s < 8; ++s) {
        e_nxt[s] = yprow[(size_t)(1 + s) * D_ + j];
        c_nxt[s] = mrow[1 + s];
    }

    // 255 full groups of 8 steps: t = 1 .. 2040
    for (int g = 0; g < 255; ++g) {
        const int tbase = 1 + 8 * g;
        #pragma unroll
        for (int s = 0; s < 8; ++s) { e_cur[s] = e_nxt[s]; c_cur[s] = c_nxt[s]; }
        // issue next group's loads: in flight for 8 full steps
        #pragma unroll
        for (int s = 0; s < 8; ++s) {
            int t = tbase + 8 + s; if (t > S_ - 1) t = S_ - 1;
            e_nxt[s] = yprow[(size_t)t * D_ + j];
            c_nxt[s] = mrow[t];
        }
        #pragma unroll
        for (int s = 0; s < 8; ++s) ex[s] = __expf(e_cur[s]);
        #pragma unroll
        for (int s = 0; s < 8; ++s)
            step(e_cur[s], ex[s], c_cur[s], (s == 3) || (s == 7));
    }
    // tail: t = 2041..2047 (7 steps), values already in e_nxt[0..6]
    #pragma unroll
    for (int s = 0; s < 7; ++s) ex[s] = __expf(e_nxt[s]);
    #pragma unroll
    for (int s = 0; s < 7; ++s)
        step(e_nxt[s], ex[s], c_nxt[s], (s == 3));

    // logZ = K*ln2 + Of + log(sum_j p_j);  out = logZ - target
    float fs = p;
    #pragma unroll
    for (int m = 1; m <= 32; m <<= 1) fs += __shfl_xor(fs, m, 64);
    if (j == 0) {
        float logz = (float)((double)K * 0.6931471805599453) + Of + __logf(fs);
        out[b] = logz - target[b];
    }
}

extern "C" void kernel_launch(void* const* d_in, const int* in_sizes, int n_in,
                              void* d_out, int out_size, void* d_ws, size_t ws_size,
                              hipStream_t stream)
{
    const float* y_pred = (const float*)d_in[0];
    const int*   y_true = (const int*)d_in[1];
    const float* mask   = (const float*)d_in[2];
    const float* trans  = (const float*)d_in[3];
    float* outp   = (float*)d_out;
    float* target = (float*)d_ws;   // 256 floats of scratch

    hipLaunchKernelGGL(target_kernel, dim3(B_), dim3(256), 0, stream,
                       y_pred, y_true, mask, trans, target);
    hipLaunchKernelGGL(scan_kernel, dim3(B_), dim3(64), 0, stream,
                       y_pred, mask, trans, target, outp);
}

// Round 5
// 654.079 us; speedup vs baseline: 1.5748x; 1.5748x over previous
//
#include <hip/hip_runtime.h>

// CRF loss: out[b] = logZ[b] - target[b].  B=256, S=2048, D=64.
// Round 5: MFMA formulation. PT' = ET^T @ PT with v_mfma_f32_16x16x16_bf16,
//          16 batches/wave, D-fragment feeds next B-fragment with no
//          cross-lane movement. exp(e) precomputed to ws as permuted bf16
//          table. Fallback to round-3 kernel if ws too small.

#define B_ 256
#define S_ 2048
#define D_ 64

typedef float  f32x2 __attribute__((ext_vector_type(2)));
typedef float  f32x4 __attribute__((ext_vector_type(4)));
typedef short  v4s   __attribute__((ext_vector_type(4)));

// ws layout (fast path)
#define OFF_FLG   4096
#define OFF_CM    (OFF_FLG + 2048*16*4)
#define OFF_EXPE  (OFF_CM + 2048*16*16*4)
#define WS_NEEDED ((size_t)OFF_EXPE + (size_t)2047*16*512*4)

#if __has_builtin(__builtin_amdgcn_mfma_f32_16x16x16bf16_1k)
static __device__ __forceinline__ f32x4 mfma16(v4s a, v4s b, f32x4 cc) {
    return __builtin_amdgcn_mfma_f32_16x16x16bf16_1k(a, b, cc, 0, 0, 0);
}
#else
static __device__ __forceinline__ f32x4 mfma16(v4s a, v4s b, f32x4 cc) {
    f32x4 d;
    asm("v_mfma_f32_16x16x16_bf16 %0, %1, %2, %3"
        : "=&v"(d) : "v"(a), "v"(b), "v"(cc));
    return d;
}
#endif

static __device__ __forceinline__ unsigned cvtpk_bf16(float lo, float hi) {
    unsigned w;
    asm("v_cvt_pk_bf16_f32 %0, %1, %2" : "=v"(w) : "v"(lo), "v"(hi));
    return w;
}

// ---------------- target scores: point + transition ----------------
__global__ __launch_bounds__(256) void target_kernel(
    const float* __restrict__ y_pred, const int* __restrict__ y_true,
    const float* __restrict__ mask, const float* __restrict__ trans,
    float* __restrict__ target)
{
    int b = blockIdx.x;
    int tid = threadIdx.x;
    const int*   yt = y_true + (size_t)b * S_;
    const float* mk = mask   + (size_t)b * S_;
    const float* yp = y_pred + (size_t)b * S_ * D_;

    float acc = 0.f;
    for (int n = tid; n < S_; n += 256) {
        int   tn = yt[n];
        float mn = mk[n];
        acc += mn * mn * yp[(size_t)n * D_ + tn];
        if (n + 1 < S_) {
            int   tn1 = yt[n + 1];
            float mn1 = mk[n + 1];
            acc += mn * mn1 * trans[tn * D_ + tn1];
        }
    }
    #pragma unroll
    for (int m = 32; m >= 1; m >>= 1) acc += __shfl_xor(acc, m, 64);
    __shared__ float sred[4];
    int wid = tid >> 6;
    if ((tid & 63) == 0) sred[wid] = acc;
    __syncthreads();
    if (tid == 0) target[b] = sred[0] + sred[1] + sred[2] + sred[3];
}

// ---------------- expe table: permuted bf16 exp(y_pred) ----------------
// word W = ((tm1*16 + bg)*64 + lane)*8 + slot; slot k=(m,q): states
// s = 16m + 4g + 2q, s+1 of batch bg*16+c   (lane = (g<<4)|c)
__global__ __launch_bounds__(256) void expe_kernel(
    const float* __restrict__ y_pred, unsigned* __restrict__ expe)
{
    unsigned W = blockIdx.x * 256u + threadIdx.x;   // exactly 2047*16*512 threads
    unsigned k   = W & 7u;
    unsigned l   = (W >> 3) & 63u;
    unsigned bg  = (W >> 9) & 15u;
    unsigned tm1 = W >> 13;
    unsigned g = l >> 4, c = l & 15u;
    unsigned m = k >> 1, q = k & 1u;
    unsigned s = 16u * m + 4u * g + 2u * q;
    unsigned b = bg * 16u + c;
    const float* src = y_pred + ((size_t)b * S_ + (tm1 + 1)) * D_ + s;
    float e0 = __expf(src[0]), e1 = __expf(src[1]);
    expe[W] = cvtpk_bf16(e0, e1);
}

// ---------------- per-step mask flags + cm values ----------------
__global__ __launch_bounds__(256) void flags_kernel(
    const float* __restrict__ mask, unsigned* __restrict__ flags,
    float* __restrict__ cmtab)
{
    unsigned idx = blockIdx.x * 256u + threadIdx.x;
    if (idx >= 2047u * 16u) return;
    unsigned bg = idx & 15u, tm1 = idx >> 4;
    unsigned t = tm1 + 1u;
    unsigned allone = 1u;
    #pragma unroll
    for (int i = 0; i < 16; ++i) {
        float cm = mask[(size_t)(bg * 16u + i) * S_ + t];
        if (cm != 1.0f) allone = 0u;
        cmtab[(size_t)idx * 16 + i] = cm;
    }
    flags[idx] = allone;
}

// ---------------- MFMA forward scan: 16 batches per wave ----------------
__global__ __launch_bounds__(64, 1) void mfma_scan_kernel(
    const float* __restrict__ y_pred, const float* __restrict__ mask,
    const float* __restrict__ trans, const float* __restrict__ target,
    const unsigned* __restrict__ expe, const unsigned* __restrict__ flags,
    const float* __restrict__ cmtab, float* __restrict__ out)
{
    const int bg = blockIdx.x;          // batch group (16 batches)
    const int l  = threadIdx.x;
    const int g  = l >> 4, c = l & 15;
    const int b0 = bg * 16;

    // A fragments (stationary): Av[m][kt] elem e = exp(trans[16kt+4g+e][16m+c])
    v4s Av[4][4];
    #pragma unroll
    for (int m = 0; m < 4; ++m)
        #pragma unroll
        for (int kt = 0; kt < 4; ++kt) {
            float a0 = __expf(trans[(16*kt + 4*g + 0) * D_ + 16*m + c]);
            float a1 = __expf(trans[(16*kt + 4*g + 1) * D_ + 16*m + c]);
            float a2 = __expf(trans[(16*kt + 4*g + 2) * D_ + 16*m + c]);
            float a3 = __expf(trans[(16*kt + 4*g + 3) * D_ + 16*m + c]);
            union { uint2 u; v4s s; } uu;
            uu.u.x = cvtpk_bf16(a0, a1); uu.u.y = cvtpk_bf16(a2, a3);
            Av[m][kt] = uu.s;
        }

    // init state: B[kt] elem e = exp(y_pred[b0+c][0][16kt+4g+e] * m0), bf16
    v4s Bv[4];
    {
        float m0 = mask[(size_t)(b0 + c) * S_];
        const float* yp0 = y_pred + (size_t)(b0 + c) * S_ * D_;
        #pragma unroll
        for (int kt = 0; kt < 4; ++kt) {
            float p0 = __expf(yp0[16*kt + 4*g + 0] * m0);
            float p1 = __expf(yp0[16*kt + 4*g + 1] * m0);
            float p2 = __expf(yp0[16*kt + 4*g + 2] * m0);
            float p3 = __expf(yp0[16*kt + 4*g + 3] * m0);
            union { uint2 u; v4s s; } uu;
            uu.u.x = cvtpk_bf16(p0, p1); uu.u.y = cvtpk_bf16(p2, p3);
            Bv[kt] = uu.s;
        }
    }

    int K = 0;   // wave-uniform exact power-of-2 offset (logZ += K*ln2)

    auto stepf = [&](uint4 ea, uint4 eb, unsigned flagw, int tm1) {
        // PT' = ET^T @ PT : 4 M-tiles x 4 K-tiles of 16x16x16 bf16 MFMA
        f32x4 acc[4];
        #pragma unroll
        for (int m = 0; m < 4; ++m) { f32x4 z = {0.f, 0.f, 0.f, 0.f}; acc[m] = z; }
        #pragma unroll
        for (int kt = 0; kt < 4; ++kt)
            #pragma unroll
            for (int m = 0; m < 4; ++m)
                acc[m] = mfma16(Av[m][kt], Bv[kt], acc[m]);

        // multiply by exp(e): slot (m,q) word = bf16 pair (state 16m+4g+2q, +1)
        unsigned ws_[8] = {ea.x, ea.y, ea.z, ea.w, eb.x, eb.y, eb.z, eb.w};
        f32x2 pr[4][2];
        #pragma unroll
        for (int m = 0; m < 4; ++m)
            #pragma unroll
            for (int q = 0; q < 2; ++q) {
                unsigned w = ws_[m * 2 + q];
                f32x2 ep; ep.x = __uint_as_float(w << 16);
                          ep.y = __uint_as_float(w & 0xffff0000u);
                f32x2 av; av.x = acc[m][2*q]; av.y = acc[m][2*q + 1];
                pr[m][q] = av * ep;
            }

        // mask select (exact for 0/1 masks; inputs here are all-ones)
        if (__builtin_expect(flagw == 0u, 0)) {
            float cmv = cmtab[((size_t)tm1 * 16 + bg) * 16 + c];
            bool keep = (cmv != 1.0f);
            #pragma unroll
            for (int m = 0; m < 4; ++m)
                #pragma unroll
                for (int q = 0; q < 2; ++q) {
                    float o0 = __uint_as_float(((unsigned)(unsigned short)Bv[m][2*q])     << 16);
                    float o1 = __uint_as_float(((unsigned)(unsigned short)Bv[m][2*q + 1]) << 16);
                    pr[m][q].x = keep ? o0 : pr[m][q].x;
                    pr[m][q].y = keep ? o1 : pr[m][q].y;
                }
        }

        // exact pow2 renorm keyed off lane0 (batch0,state0) exponent
        unsigned rep = __builtin_amdgcn_readfirstlane(__float_as_uint(pr[0][0].x));
        int k = (int)((rep >> 23) & 0xffu) - 127;
        if (__builtin_expect(k > 48 || k < -48, 0)) {
            float sc = __uint_as_float((unsigned)(127 - k) << 23);
            #pragma unroll
            for (int m = 0; m < 4; ++m)
                #pragma unroll
                for (int q = 0; q < 2; ++q) { pr[m][q].x *= sc; pr[m][q].y *= sc; }
            K += k;
        }

        // pack back to bf16 B operands (D reg r -> B elem e, same tile index)
        #pragma unroll
        for (int m = 0; m < 4; ++m) {
            union { uint2 u; v4s s; } uu;
            uu.u.x = cvtpk_bf16(pr[m][0].x, pr[m][0].y);
            uu.u.y = cvtpk_bf16(pr[m][1].x, pr[m][1].y);
            Bv[m] = uu.s;
        }
    };

    // 8-step ping-pong prefetch of expe words (2 x dwordx4 / step) + flag
    const unsigned* ebase = expe + (size_t)bg * 512 + (size_t)l * 8;
    uint4 eA[8][2], eB[8][2];
    unsigned fA[8], fB[8];

    auto loadgrp = [&](int t0, uint4 (&e)[8][2], unsigned (&f)[8]) {
        #pragma unroll
        for (int s = 0; s < 8; ++s) {
            int tm1 = t0 + s - 1; if (tm1 > 2046) tm1 = 2046;
            const uint4* p = (const uint4*)(ebase + (size_t)tm1 * 8192);
            e[s][0] = p[0];
            e[s][1] = p[1];
            f[s] = flags[(size_t)tm1 * 16 + bg];
        }
    };

    loadgrp(1, eA, fA);
    for (int grp = 0; grp < 255; ++grp) {
        int t0 = 1 + grp * 8;
        if ((grp & 1) == 0) {
            loadgrp(t0 + 8, eB, fB);
            #pragma unroll
            for (int s = 0; s < 8; ++s) stepf(eA[s][0], eA[s][1], fA[s], t0 + s - 1);
        } else {
            loadgrp(t0 + 8, eA, fA);
            #pragma unroll
            for (int s = 0; s < 8; ++s) stepf(eB[s][0], eB[s][1], fB[s], t0 + s - 1);
        }
    }
    // tail t = 2041..2047 (7 steps; group 255 was loaded into eB at grp=254)
    #pragma unroll
    for (int s = 0; s < 7; ++s) stepf(eB[s][0], eB[s][1], fB[s], 2040 + s);

    // logZ[b] = K*ln2 + log(sum_j p_j[b]);  out = logZ - target
    float fs = 0.f;
    #pragma unroll
    for (int m = 0; m < 4; ++m)
        #pragma unroll
        for (int e = 0; e < 4; ++e)
            fs += __uint_as_float(((unsigned)(unsigned short)Bv[m][e]) << 16);
    fs += __shfl_xor(fs, 16, 64);
    fs += __shfl_xor(fs, 32, 64);
    if (l < 16) {
        float logz = (float)((double)K * 0.6931471805599453) + __logf(fs);
        out[b0 + l] = logz - target[b0 + l];
    }
}

// ---------------- fallback scan (round-3, proven): one wave per batch ------
typedef float f32x2b __attribute__((ext_vector_type(2)));
static __device__ __forceinline__ f32x2 mk2(float a, float b) {
    f32x2 r; r.x = a; r.y = b; return r;
}

__global__ __launch_bounds__(64) void scan_kernel(
    const float* __restrict__ y_pred, const float* __restrict__ mask,
    const float* __restrict__ trans, const float* __restrict__ target,
    float* __restrict__ out)
{
    const int b = blockIdx.x;
    const int j = threadIdx.x;
    const float* yprow = y_pred + (size_t)b * S_ * D_;
    const float* mrow  = mask   + (size_t)b * S_;

    f32x2 et2[32];
    #pragma unroll
    for (int c = 0; c < 32; ++c) {
        et2[c].x = __expf(trans[(2 * c + 0) * D_ + j]);
        et2[c].y = __expf(trans[(2 * c + 1) * D_ + j]);
    }

    __shared__ float4 sp4[16];
    float p  = __expf(yprow[j] * mrow[0]);
    int   K  = 0;
    float Of = 0.f;
    ((float*)sp4)[j] = p;

    auto step = [&](float eraw, float exs, float cs, bool dorescale) {
        const float4* pb = sp4;
        f32x2 a0 = mk2(0.f, 0.f), a1 = a0, a2 = a0, a3 = a0,
              a4 = a0, a5 = a0, a6 = a0, a7 = a0;
        #pragma unroll
        for (int c = 0; c < 16; c += 4) {
            float4 u0 = pb[c], u1 = pb[c + 1], u2 = pb[c + 2], u3 = pb[c + 3];
            a0 = __builtin_elementwise_fma(mk2(u0.x, u0.y), et2[2 * c + 0], a0);
            a1 = __builtin_elementwise_fma(mk2(u0.z, u0.w), et2[2 * c + 1], a1);
            a2 = __builtin_elementwise_fma(mk2(u1.x, u1.y), et2[2 * c + 2], a2);
            a3 = __builtin_elementwise_fma(mk2(u1.z, u1.w), et2[2 * c + 3], a3);
            a4 = __builtin_elementwise_fma(mk2(u2.x, u2.y), et2[2 * c + 4], a4);
            a5 = __builtin_elementwise_fma(mk2(u2.z, u2.w), et2[2 * c + 5], a5);
            a6 = __builtin_elementwise_fma(mk2(u3.x, u3.y), et2[2 * c + 6], a6);
            a7 = __builtin_elementwise_fma(mk2(u3.z, u3.w), et2[2 * c + 7], a7);
        }
        f32x2 s01 = (a0 + a1) + (a2 + a3);
        f32x2 s23 = (a4 + a5) + (a6 + a7);
        f32x2 st  = s01 + s23;
        float sum = st.x + st.y;

        if (cs == 1.0f) {
            p = sum * exs;
        } else {
            float sj   = __logf(p);
            float outn = __logf(sum) + eraw * cs;
            float ns   = cs * outn + (1.f - cs) * sj;
            float M = ns;
            #pragma unroll
            for (int m = 1; m <= 32; m <<= 1) M = fmaxf(M, __shfl_xor(M, m, 64));
            p = __expf(ns - M);
            Of += M;
        }
        if (dorescale) {
            unsigned pb0 = __builtin_amdgcn_readfirstlane(__float_as_uint(p));
            int k = (int)((pb0 >> 23) & 0xffu) - 127;
            float sc = __uint_as_float((unsigned)(127 - k) << 23);
            p *= sc;
            K += k;
        }
        ((float*)sp4)[j] = p;
    };

    float e_nxt[8], c_nxt[8], e_cur[8], c_cur[8], ex[8];
    #pragma unroll
    for (int s = 0; s < 8; ++s) {
        e_nxt[s] = yprow[(size_t)(1 + s) * D_ + j];
        c_nxt[s] = mrow[1 + s];
    }
    for (int g = 0; g < 255; ++g) {
        const int tbase = 1 + 8 * g;
        #pragma unroll
        for (int s = 0; s < 8; ++s) { e_cur[s] = e_nxt[s]; c_cur[s] = c_nxt[s]; }
        #pragma unroll
        for (int s = 0; s < 8; ++s) {
            int t = tbase + 8 + s; if (t > S_ - 1) t = S_ - 1;
            e_nxt[s] = yprow[(size_t)t * D_ + j];
            c_nxt[s] = mrow[t];
        }
        #pragma unroll
        for (int s = 0; s < 8; ++s) ex[s] = __expf(e_cur[s]);
        #pragma unroll
        for (int s = 0; s < 8; ++s)
            step(e_cur[s], ex[s], c_cur[s], (s == 3) || (s == 7));
    }
    #pragma unroll
    for (int s = 0; s < 7; ++s) ex[s] = __expf(e_nxt[s]);
    #pragma unroll
    for (int s = 0; s < 7; ++s)
        step(e_nxt[s], ex[s], c_nxt[s], (s == 3));

    float fs = p;
    #pragma unroll
    for (int m = 1; m <= 32; m <<= 1) fs += __shfl_xor(fs, m, 64);
    if (j == 0) {
        float logz = (float)((double)K * 0.6931471805599453) + Of + __logf(fs);
        out[b] = logz - target[b];
    }
}

extern "C" void kernel_launch(void* const* d_in, const int* in_sizes, int n_in,
                              void* d_out, int out_size, void* d_ws, size_t ws_size,
                              hipStream_t stream)
{
    const float* y_pred = (const float*)d_in[0];
    const int*   y_true = (const int*)d_in[1];
    const float* mask   = (const float*)d_in[2];
    const float* trans  = (const float*)d_in[3];
    float* outp   = (float*)d_out;
    float* target = (float*)d_ws;   // 256 floats of scratch

    hipLaunchKernelGGL(target_kernel, dim3(B_), dim3(256), 0, stream,
                       y_pred, y_true, mask, trans, target);

    if (ws_size >= WS_NEEDED) {
        unsigned* flags = (unsigned*)((char*)d_ws + OFF_FLG);
        float*    cmtab = (float*)((char*)d_ws + OFF_CM);
        unsigned* expe  = (unsigned*)((char*)d_ws + OFF_EXPE);
        hipLaunchKernelGGL(flags_kernel, dim3(128), dim3(256), 0, stream,
                           mask, flags, cmtab);
        hipLaunchKernelGGL(expe_kernel, dim3(65504), dim3(256), 0, stream,
                           y_pred, expe);
        hipLaunchKernelGGL(mfma_scan_kernel, dim3(16), dim3(64), 0, stream,
                           y_pred, mask, trans, target, expe, flags, cmtab, outp);
    } else {
        hipLaunchKernelGGL(scan_kernel, dim3(B_), dim3(64), 0, stream,
                           y_pred, mask, trans, target, outp);
    }
}